// Round 1
// baseline (803.623 us; speedup 1.0000x reference)
//
#include <hip/hip_runtime.h>

// Spherical harmonics, L=20 (400 columns), B=250000 points, fp32.
// One thread per point; fully unrolled l-major recurrence; compile-time
// normalization table (folds to literals); ascending-address row writes.

#define L_MAX 20
#define NCOL (L_MAX * L_MAX)   // 400

// ---- compile-time double sqrt via Newton (handles 1e-45..1e2 fine) ----
constexpr double csqrt(double x) {
    double g = (x > 1.0) ? x : 1.0;
    for (int i = 0; i < 200; ++i) g = 0.5 * (g + x / g);
    return g;
}

struct CoefTbl { float c[NCOL]; };

constexpr CoefTbl make_tbl() {
    CoefTbl t{};
    const double PI  = 3.14159265358979323846;
    const double SQ2 = csqrt(2.0);
    for (int l = 0; l < L_MAX; ++l) {
        for (int m = 0; m <= l; ++m) {
            // ratio = (l-m)! / (l+m)!  computed as product of reciprocals (double: no subnormals)
            double r = 1.0;
            for (int k = l - m + 1; k <= l + m; ++k) r /= (double)k;
            double K = csqrt((2.0 * l + 1.0) / (4.0 * PI) * r);
            int base = l * l + l;
            if (m == 0) {
                t.c[base] = (float)K;
            } else {
                t.c[base + m] = (float)(SQ2 * K);   // cos term
                t.c[base - m] = (float)(SQ2 * K);   // sin term (same coefficient)
            }
        }
    }
    return t;
}

static constexpr CoefTbl TBL = make_tbl();

__global__ __launch_bounds__(256) void sh_kernel(const float2* __restrict__ lonlat,
                                                 float* __restrict__ out, int B) {
    int p = blockIdx.x * blockDim.x + threadIdx.x;
    if (p >= B) return;

    float2 ll = lonlat[p];
    const float D2R = 0.017453292519943295f;  // pi/180
    float phi   = (ll.x + 180.0f) * D2R;
    float theta = (ll.y + 90.0f) * D2R;

    float x  = cosf(theta);
    float sx = sinf(theta);
    float s1, c1;
    sincosf(phi, &s1, &c1);

    // cos(m*phi), sin(m*phi) via Chebyshev/angle-addition recurrence
    float cm[L_MAX], sm[L_MAX];
    cm[0] = 1.0f; sm[0] = 0.0f;
#pragma unroll
    for (int m = 1; m < L_MAX; ++m) {
        cm[m] = cm[m - 1] * c1 - sm[m - 1] * s1;
        sm[m] = sm[m - 1] * c1 + cm[m - 1] * s1;
    }

    float* row = out + (size_t)p * NCOL;

    float A[L_MAX];   // P[l-1][m]
    float Bv[L_MAX];  // P[l-2][m]
    float C[L_MAX];   // P[l][m]
    float pmm = 1.0f; // P[l][l] chain

#pragma unroll
    for (int l = 0; l < L_MAX; ++l) {
        // --- compute row l of associated Legendre ---
#pragma unroll
        for (int m = 0; m <= l - 2; ++m) {
            C[m] = (float(2 * l - 1) * x * A[m] - float(l + m - 1) * Bv[m]) * (1.0f / float(l - m));
        }
        if (l >= 1) {
            C[l - 1] = float(2 * l - 1) * x * A[l - 1];   // P[m+1][m], m = l-1
            pmm = -float(2 * l - 1) * sx * pmm;           // P[l][l]
        }
        C[l] = pmm;

        // --- emit columns for row l (ascending-ish addresses within [l^2, l^2+2l]) ---
        const int base = l * l + l;
        row[base] = TBL.c[base] * C[0];
#pragma unroll
        for (int m = 1; m <= l; ++m) {
            float t = TBL.c[base + m] * C[m];
            row[base + m] = t * cm[m];
            row[base - m] = t * sm[m];
        }

        // --- rotate rolling rows ---
#pragma unroll
        for (int m = 0; m <= l; ++m) { Bv[m] = A[m]; A[m] = C[m]; }
    }
}

extern "C" void kernel_launch(void* const* d_in, const int* in_sizes, int n_in,
                              void* d_out, int out_size, void* d_ws, size_t ws_size,
                              hipStream_t stream) {
    (void)n_in; (void)d_ws; (void)ws_size; (void)out_size;
    const float2* lonlat = (const float2*)d_in[0];
    float* out = (float*)d_out;
    int B = in_sizes[0] / 2;  // lonlat is [B,2] flat

    const int threads = 256;
    const int blocks = (B + threads - 1) / threads;
    sh_kernel<<<blocks, threads, 0, stream>>>(lonlat, out, B);
}

// Round 2
// 459.352 us; speedup vs baseline: 1.7495x; 1.7495x over previous
//
#include <hip/hip_runtime.h>

// Spherical harmonics, L=20 (400 cols), B=250000, fp32 out.
// R2: LDS-staged coalesced writes. 64 points/block, 256 threads (4 waves
// redundantly compute, partition column writes by m&3 — wave-uniform).
// Two column chunks ([0,196) and [196,400)) share one 64x205 LDS tile;
// cooperative flush emits contiguous 256B runs per wave, and each block
// fully covers a contiguous 100KB global region -> ~1.0x write traffic.

#define L_MAX 20
#define NCOL 400
#define PTS 64          // points per block
#define TPB 256         // 4 waves
#define LSTR 205        // LDS row stride (floats), odd -> conflict-free
#define SPLIT_L 14      // 14*14 = 196
#define C0A 0
#define CA 196
#define C0B 196
#define CB 204

// ---- compile-time double sqrt via Newton ----
constexpr double csqrt(double x) {
    double g = (x > 1.0) ? x : 1.0;
    for (int i = 0; i < 200; ++i) g = 0.5 * (g + x / g);
    return g;
}

struct CoefTbl { float c[NCOL]; };

constexpr CoefTbl make_tbl() {
    CoefTbl t{};
    const double PI  = 3.14159265358979323846;
    const double SQ2 = csqrt(2.0);
    for (int l = 0; l < L_MAX; ++l) {
        for (int m = 0; m <= l; ++m) {
            double r = 1.0;
            for (int k = l - m + 1; k <= l + m; ++k) r /= (double)k;
            double K = csqrt((2.0 * l + 1.0) / (4.0 * PI) * r);
            int base = l * l + l;
            if (m == 0) {
                t.c[base] = (float)K;
            } else {
                t.c[base + m] = (float)(SQ2 * K);
                t.c[base - m] = (float)(SQ2 * K);
            }
        }
    }
    return t;
}

static constexpr CoefTbl TBL = make_tbl();

__global__ __launch_bounds__(TPB, 3) void sh_kernel(const float2* __restrict__ lonlat,
                                                    float* __restrict__ out, int B) {
    __shared__ float tile[PTS * LSTR];

    const int tid  = threadIdx.x;
    const int lane = tid & 63;     // point within block
    const int sub  = tid >> 6;     // redundant-compute wave id (uniform per wave)
    const int blockBase = blockIdx.x * PTS;
    const int p  = blockBase + lane;
    const int pr = p < B ? p : B - 1;

    float2 ll = lonlat[pr];
    const float D2R = 0.017453292519943295f;
    float phi   = (ll.x + 180.0f) * D2R;
    float theta = (ll.y + 90.0f) * D2R;

    float x, sx, s1, c1;
    sincosf(theta, &sx, &x);   // sx = sin(theta), x = cos(theta)
    sincosf(phi, &s1, &c1);

    float cm[L_MAX], sm[L_MAX];
    cm[0] = 1.0f; sm[0] = 0.0f;
#pragma unroll
    for (int m = 1; m < L_MAX; ++m) {
        cm[m] = cm[m - 1] * c1 - sm[m - 1] * s1;
        sm[m] = sm[m - 1] * c1 + cm[m - 1] * s1;
    }

    float Pa[L_MAX], Pb[L_MAX], Pc[L_MAX];
    float pmm = 1.0f;
    float* myrow = tile + lane * LSTR;

    auto emit = [&](int l, int c0) {
#pragma unroll
        for (int m = 0; m <= l - 2; ++m)
            Pc[m] = (float(2 * l - 1) * x * Pa[m] - float(l + m - 1) * Pb[m]) * (1.0f / float(l - m));
        if (l >= 1) {
            Pc[l - 1] = float(2 * l - 1) * x * Pa[l - 1];
            pmm = -float(2 * l - 1) * sx * pmm;
        }
        Pc[l] = pmm;

        const int gbase = l * l + l;       // global column of m=0
        const int base  = gbase - c0;      // LDS-local column
        if (sub == 0) myrow[base] = TBL.c[gbase] * Pc[0];
#pragma unroll
        for (int m = 1; m <= l; ++m) {
            if ((m & 3) == sub) {          // wave-uniform partition
                float t = TBL.c[gbase + m] * Pc[m];
                myrow[base + m] = t * cm[m];
                myrow[base - m] = t * sm[m];
            }
        }
#pragma unroll
        for (int m = 0; m <= l; ++m) { Pb[m] = Pa[m]; Pa[m] = Pc[m]; }
    };

    // ---- chunk A: l = 0..13 -> global cols [0,196) ----
#pragma unroll
    for (int l = 0; l < SPLIT_L; ++l) emit(l, C0A);

    __syncthreads();
    for (int i = tid; i < PTS * CA; i += TPB) {
        int pp = i / CA;                   // constant divisor -> magic mul
        int cc = i - pp * CA;
        int gp = blockBase + pp;
        if (gp < B) out[(size_t)gp * NCOL + C0A + cc] = tile[pp * LSTR + cc];
    }
    __syncthreads();

    // ---- chunk B: l = 14..19 -> global cols [196,400), stored at col-196 ----
#pragma unroll
    for (int l = SPLIT_L; l < L_MAX; ++l) emit(l, C0B);

    __syncthreads();
    for (int i = tid; i < PTS * CB; i += TPB) {
        int pp = i / CB;
        int cc = i - pp * CB;
        int gp = blockBase + pp;
        if (gp < B) out[(size_t)gp * NCOL + C0B + cc] = tile[pp * LSTR + cc];
    }
}

extern "C" void kernel_launch(void* const* d_in, const int* in_sizes, int n_in,
                              void* d_out, int out_size, void* d_ws, size_t ws_size,
                              hipStream_t stream) {
    (void)n_in; (void)d_ws; (void)ws_size; (void)out_size;
    const float2* lonlat = (const float2*)d_in[0];
    float* out = (float*)d_out;
    int B = in_sizes[0] / 2;

    const int blocks = (B + PTS - 1) / PTS;
    sh_kernel<<<blocks, TPB, 0, stream>>>(lonlat, out, B);
}